// Round 1
// baseline (1338.998 us; speedup 1.0000x reference)
//
#include <hip/hip_runtime.h>
#include <math.h>

// Problem constants: S=512, B=32, R=8, H=128, TOP=3, CHL=19, I=20
//
// Pipeline:
//  kT   : transpose Kir,Vir (H,S)->(S,H) and Vrr (H,H)->(H,H)^T
//  kKV  : k[b,i,o], v[b,i,o]  (i=0 null -> 0)
//  kKQ  : KQ[b,i,h] = sum_o k[b,i,o]*Qir[o,h];  cb[b,i] = k[b,i,:].Qir_b
//  kM   : M = Qrr^T @ Krr   (for qk2 = h1 M h1^T)
//  kGRU : 512-step GRU, one block per (r,b), h -> hs (S,B,R,H)
//  kS1  : stage-1 attention: qk via KQ fold, softmax, top-3 -> h1, widx
//  kS2  : stage-2: t1 = h1[w] @ M, qk2, softmax, u = s2@h1, out = h1 + u@Vrr^T (winners), losers 0

// ---------------- transposes ----------------
__global__ void kT(const float* __restrict__ Kir, const float* __restrict__ Vir,
                   const float* __restrict__ Vrr,
                   float* __restrict__ KirT, float* __restrict__ VirT,
                   float* __restrict__ VrrT) {
    int idx = blockIdx.x * 256 + threadIdx.x;
    if (idx < 65536) {
        int s = idx >> 7, o = idx & 127;
        KirT[idx] = Kir[o * 512 + s];
    } else if (idx < 131072) {
        int j = idx - 65536;
        int s = j >> 7, o = j & 127;
        VirT[j] = Vir[o * 512 + s];
    } else if (idx < 147456) {
        int j = idx - 131072;
        int g = j >> 7, h = j & 127;
        VrrT[j] = Vrr[h * 128 + g];
    }
}

// ---------------- k, v ----------------
__global__ __launch_bounds__(128) void kKV(const float* __restrict__ x,
        const float* __restrict__ KirT, const float* __restrict__ VirT,
        float* __restrict__ kbuf, float* __restrict__ vbuf) {
    const int b = blockIdx.x / 20, i = blockIdx.x % 20;
    const int o = threadIdx.x;
    if (i == 0) {  // null channel: x_bis[b,0,:] == 0
        kbuf[(b * 20) * 128 + o] = 0.0f;
        vbuf[(b * 20) * 128 + o] = 0.0f;
        return;
    }
    __shared__ float xL[512];
    for (int idx = threadIdx.x; idx < 512; idx += 128)
        xL[idx] = x[(b * 19 + (i - 1)) * 512 + idx];
    __syncthreads();
    float ak = 0.0f, av = 0.0f;
#pragma unroll 4
    for (int s = 0; s < 512; ++s) {
        float xv = xL[s];
        ak += xv * KirT[s * 128 + o];
        av += xv * VirT[s * 128 + o];
    }
    kbuf[(b * 20 + i) * 128 + o] = ak;
    vbuf[(b * 20 + i) * 128 + o] = av;
}

// ---------------- KQ fold + cb ----------------
__global__ __launch_bounds__(128) void kKQ(const float* __restrict__ kbuf,
        const float* __restrict__ Qir, const float* __restrict__ Qib,
        float* __restrict__ KQ, float* __restrict__ cb) {
    const int b = blockIdx.x / 20, i = blockIdx.x % 20;
    const int h = threadIdx.x;
    __shared__ float kL[128];
    kL[h] = kbuf[(b * 20 + i) * 128 + h];
    __syncthreads();
    float acc = 0.0f;
#pragma unroll 4
    for (int o = 0; o < 128; ++o) acc += kL[o] * Qir[o * 128 + h];
    KQ[(b * 20 + i) * 128 + h] = acc;
    if (h == 0) {
        float c = 0.0f;
        for (int o = 0; o < 128; ++o) c += kL[o] * Qib[o];
        cb[b * 20 + i] = c;
    }
}

// ---------------- M = Qrr^T @ Krr ----------------
__global__ __launch_bounds__(256) void kM(const float* __restrict__ Qrr,
        const float* __restrict__ Krr, float* __restrict__ M) {
    const int h = blockIdx.x * 2 + (threadIdx.x >> 7);
    const int g = threadIdx.x & 127;
    float acc = 0.0f;
#pragma unroll 4
    for (int o = 0; o < 128; ++o) acc += Qrr[o * 128 + h] * Krr[o * 128 + g];
    M[h * 128 + g] = acc;
}

// ---------------- GRU ----------------
// grid 256 = (r,b); 512 threads: t = j + 128*kq; thread owns Whh rows
// {j, j+128, j+256} restricted to k-slice [32*kq, 32*kq+32).
__global__ __launch_bounds__(512) void kGRU(const float* __restrict__ x,
        const float* __restrict__ Wih, const float* __restrict__ Whh,
        float* __restrict__ hs) {
    const int r = blockIdx.x >> 5;
    const int b = blockIdx.x & 31;
    const int t = threadIdx.x;
    const int j = t & 127;
    const int kq = t >> 7;

    __shared__ __align__(16) float xT[512 * 20];  // [s][c] (c=0..18 used)
    __shared__ __align__(16) float hL[128];
    __shared__ float part[4][3][128];             // [kq][gate][j]
    __shared__ float xnL[128];                    // n-gate x-part (kept separate)

    for (int idx = t; idx < 19 * 512; idx += 512) {
        int c = idx >> 9, s = idx & 511;
        xT[s * 20 + c] = x[(b * 19 + c) * 512 + s];
    }
    if (t < 128) hL[t] = 0.0f;

    float w0[32], w1[32], w2[32];
    {
        const float* Wb = Whh + (r * 384) * 128 + kq * 32;
        const float4* s0p = (const float4*)(Wb + (j) * 128);
        const float4* s1p = (const float4*)(Wb + (j + 128) * 128);
        const float4* s2p = (const float4*)(Wb + (j + 256) * 128);
#pragma unroll
        for (int u = 0; u < 8; ++u) {
            float4 a = s0p[u]; w0[4*u] = a.x; w0[4*u+1] = a.y; w0[4*u+2] = a.z; w0[4*u+3] = a.w;
            float4 bb = s1p[u]; w1[4*u] = bb.x; w1[4*u+1] = bb.y; w1[4*u+2] = bb.z; w1[4*u+3] = bb.w;
            float4 cc = s2p[u]; w2[4*u] = cc.x; w2[4*u+1] = cc.y; w2[4*u+2] = cc.z; w2[4*u+3] = cc.w;
        }
    }
    float wi[19];
    if (kq < 3) {
        const float* W = Wih + (r * 384 + (j + 128 * kq)) * 20;
#pragma unroll
        for (int c = 0; c < 19; ++c) wi[c] = W[c + 1];  // col 0 is null channel
    }
    __syncthreads();

    const int outBase = (b * 8 + r) * 128 + j;
    for (int s = 0; s < 512; ++s) {
        float4 hv[8];
        const float4* hp4 = ((const float4*)hL) + kq * 8;
#pragma unroll
        for (int u = 0; u < 8; ++u) hv[u] = hp4[u];
        float p0 = 0.0f, p1 = 0.0f, p2 = 0.0f;
#pragma unroll
        for (int u = 0; u < 8; ++u) {
            float4 h4 = hv[u];
            p0 += w0[4*u+0]*h4.x; p1 += w1[4*u+0]*h4.x; p2 += w2[4*u+0]*h4.x;
            p0 += w0[4*u+1]*h4.y; p1 += w1[4*u+1]*h4.y; p2 += w2[4*u+1]*h4.y;
            p0 += w0[4*u+2]*h4.z; p1 += w1[4*u+2]*h4.z; p2 += w2[4*u+2]*h4.z;
            p0 += w0[4*u+3]*h4.w; p1 += w1[4*u+3]*h4.w; p2 += w2[4*u+3]*h4.w;
        }
        if (kq < 3) {
            const float4* xp4 = (const float4*)(xT + s * 20);
            float4 xa = xp4[0], xb = xp4[1], xc = xp4[2], xd = xp4[3], xe = xp4[4];
            float xp = wi[0]*xa.x + wi[1]*xa.y + wi[2]*xa.z + wi[3]*xa.w
                     + wi[4]*xb.x + wi[5]*xb.y + wi[6]*xb.z + wi[7]*xb.w
                     + wi[8]*xc.x + wi[9]*xc.y + wi[10]*xc.z + wi[11]*xc.w
                     + wi[12]*xd.x + wi[13]*xd.y + wi[14]*xd.z + wi[15]*xd.w
                     + wi[16]*xe.x + wi[17]*xe.y + wi[18]*xe.z;
            if (kq == 0) p0 += xp;
            else if (kq == 1) p1 += xp;
            else xnL[j] = xp;   // n-gate x-part must stay un-merged
        }
        part[kq][0][j] = p0;
        part[kq][1][j] = p1;
        part[kq][2][j] = p2;
        __syncthreads();
        if (t < 128) {
            float ar = part[0][0][t] + part[1][0][t] + part[2][0][t] + part[3][0][t];
            float az = part[0][1][t] + part[1][1][t] + part[2][1][t] + part[3][1][t];
            float hn = part[0][2][t] + part[1][2][t] + part[2][2][t] + part[3][2][t];
            float rg = 1.0f / (1.0f + expf(-ar));
            float zg = 1.0f / (1.0f + expf(-az));
            float ng = tanhf(xnL[t] + rg * hn);
            float hprev = hL[t];
            float hnew = (1.0f - zg) * ng + zg * hprev;
            hL[t] = hnew;
            hs[s * (32 * 8 * 128) + outBase] = hnew;
        }
        __syncthreads();
    }
}

// ---------------- stage 1 ----------------
__global__ __launch_bounds__(256) void kS1(const float* __restrict__ hs,
        const float* __restrict__ KQ, const float* __restrict__ cb,
        const float* __restrict__ vbuf,
        float* __restrict__ h1, int* __restrict__ widx) {
    const int b = blockIdx.x & 31;
    const int s0 = (blockIdx.x >> 5) * 16;
    const int t = threadIdx.x;
    __shared__ float KQL[20 * 132];
    __shared__ float vL[20 * 128];
    __shared__ float cbL[20];
    __shared__ float hLt[8 * 132];
    __shared__ float qkL[8 * 20];
    __shared__ float sfL[8 * 20];
    __shared__ float s0L[8];

    for (int idx = t; idx < 2560; idx += 256) {
        int i = idx >> 7, h = idx & 127;
        KQL[i * 132 + h] = KQ[(b * 20 + i) * 128 + h];
        vL[i * 128 + h] = vbuf[(b * 20 + i) * 128 + h];
    }
    if (t < 20) cbL[t] = cb[b * 20 + t];
    __syncthreads();

    for (int p = 0; p < 16; ++p) {
        const int s = s0 + p;
        for (int idx = t; idx < 1024; idx += 256) {
            int r = idx >> 7, h = idx & 127;
            hLt[r * 132 + h] = hs[((s * 32 + b) * 8 + r) * 128 + h];
        }
        __syncthreads();
        if (t < 152) {  // (r, i) with i=1..19; qk[...,0] is exactly 0
            int r = t / 19, i = t % 19 + 1;
            const float* hr = &hLt[r * 132];
            const float* kg = &KQL[i * 132];
            float a = 0.0f;
#pragma unroll 4
            for (int h = 0; h < 128; ++h) a += hr[h] * kg[h];
            qkL[r * 20 + i] = (a + cbL[i]) * 0.08838834764831845f;  // 1/sqrt(128)
        }
        if (t < 8) qkL[t * 20] = 0.0f;
        __syncthreads();
        if (t < 8) {
            float m = -3.4e38f;
            for (int i = 0; i < 20; ++i) m = fmaxf(m, qkL[t * 20 + i]);
            float sum = 0.0f;
            for (int i = 0; i < 20; ++i) {
                float e = expf(qkL[t * 20 + i] - m);
                sfL[t * 20 + i] = e;
                sum += e;
            }
            float inv = 1.0f / sum;
            for (int i = 0; i < 20; ++i) sfL[t * 20 + i] *= inv;
            s0L[t] = sfL[t * 20];
        }
        __syncthreads();
        if (t == 0) {  // 3 smallest soft0; ties -> lower r (stable, matches lax.top_k)
            unsigned chosen = 0;
            for (int n = 0; n < 3; ++n) {
                float best = 3.4e38f; int bi = 0;
                for (int r2 = 0; r2 < 8; ++r2) {
                    if (chosen & (1u << r2)) continue;
                    float v = s0L[r2];
                    if (v < best) { best = v; bi = r2; }
                }
                chosen |= (1u << bi);
                widx[(s * 32 + b) * 3 + n] = bi;
            }
        }
        {
            const int h = t & 127, rq = t >> 7;
            float a0 = 0, a1 = 0, a2 = 0, a3 = 0;
            for (int i = 1; i < 20; ++i) {  // v[b,0,:]==0, skip
                float vv = vL[i * 128 + h];
                a0 += sfL[(rq * 4 + 0) * 20 + i] * vv;
                a1 += sfL[(rq * 4 + 1) * 20 + i] * vv;
                a2 += sfL[(rq * 4 + 2) * 20 + i] * vv;
                a3 += sfL[(rq * 4 + 3) * 20 + i] * vv;
            }
            const int base = ((s * 32 + b) * 8 + rq * 4) * 128 + h;
            h1[base] = a0;
            h1[base + 128] = a1;
            h1[base + 256] = a2;
            h1[base + 384] = a3;
        }
        __syncthreads();
    }
}

// ---------------- stage 2 ----------------
__global__ __launch_bounds__(256) void kS2(const float* __restrict__ h1,
        const int* __restrict__ widx, const float* __restrict__ M,
        const float* __restrict__ VrrT, float* __restrict__ out) {
    const int b = blockIdx.x & 31;
    const int s0 = (blockIdx.x >> 5) * 16;
    const int t = threadIdx.x;
    extern __shared__ float dyn[];
    float* ML = dyn;            // [h][g], 16384
    float* VT = dyn + 16384;    // [g][h], 16384
    __shared__ float h1L[8 * 132];
    __shared__ float t1L[3 * 132];
    __shared__ float qk2L[3 * 8];
    __shared__ float s2L[3 * 8];
    __shared__ float uL[3 * 132];
    __shared__ int wL[3];
    __shared__ int loserL[5];

    for (int idx = t; idx < 16384; idx += 256) {
        ML[idx] = M[idx];
        VT[idx] = VrrT[idx];
    }
    __syncthreads();

    for (int p = 0; p < 16; ++p) {
        const int s = s0 + p;
        for (int idx = t; idx < 1024; idx += 256) {
            int r = idx >> 7, h = idx & 127;
            h1L[r * 132 + h] = h1[((s * 32 + b) * 8 + r) * 128 + h];
        }
        if (t == 0) {
            int a0 = widx[(s * 32 + b) * 3 + 0];
            int a1 = widx[(s * 32 + b) * 3 + 1];
            int a2 = widx[(s * 32 + b) * 3 + 2];
            wL[0] = a0; wL[1] = a1; wL[2] = a2;
            unsigned mbits = (1u << a0) | (1u << a1) | (1u << a2);
            int n = 0;
            for (int r2 = 0; r2 < 8; ++r2)
                if (!(mbits & (1u << r2))) loserL[n++] = r2;
        }
        __syncthreads();
        // t1[wr][g] = h1[winner] @ M
        for (int idx = t; idx < 384; idx += 256) {
            int wr = idx >> 7, g = idx & 127;
            const float* hr = &h1L[wL[wr] * 132];
            float a = 0.0f;
#pragma unroll 4
            for (int h = 0; h < 128; ++h) a += hr[h] * ML[h * 128 + g];
            t1L[wr * 132 + g] = a;
        }
        __syncthreads();
        if (t < 24) {
            int wr = t >> 3, c = t & 7;
            const float* ta = &t1L[wr * 132];
            const float* hc = &h1L[c * 132];
            float a = 0.0f;
#pragma unroll 4
            for (int g = 0; g < 128; ++g) a += ta[g] * hc[g];
            qk2L[wr * 8 + c] = a;
        }
        __syncthreads();
        if (t < 3) {
            float m = -3.4e38f;
            for (int c = 0; c < 8; ++c) m = fmaxf(m, qk2L[t * 8 + c]);
            float e[8];
            float sum = 0.0f;
            for (int c = 0; c < 8; ++c) { e[c] = expf(qk2L[t * 8 + c] - m); sum += e[c]; }
            float inv = 1.0f / sum;
            for (int c = 0; c < 8; ++c) s2L[t * 8 + c] = e[c] * inv;
        }
        __syncthreads();
        if (t < 128) {  // u[wr][g] = sum_c s2 * h1[c][g]
            int g = t;
            for (int wr = 0; wr < 3; ++wr) {
                float a = 0.0f;
#pragma unroll
                for (int c = 0; c < 8; ++c) a += s2L[wr * 8 + c] * h1L[c * 132 + g];
                uL[wr * 132 + g] = a;
            }
        }
        __syncthreads();
        // winners: out = h1 + u @ Vrr^T
        for (int idx = t; idx < 384; idx += 256) {
            int wr = idx >> 7, h = idx & 127;
            const float* ur = &uL[wr * 132];
            float a = h1L[wL[wr] * 132 + h];
#pragma unroll 4
            for (int g = 0; g < 128; ++g) a += ur[g] * VT[g * 128 + h];
            out[((s * 32 + b) * 8 + wL[wr]) * 128 + h] = a;
        }
        // losers: zero
        for (int idx = t; idx < 640; idx += 256) {
            int l = idx >> 7, h = idx & 127;
            out[((s * 32 + b) * 8 + loserL[l]) * 128 + h] = 0.0f;
        }
        __syncthreads();
    }
}

extern "C" void kernel_launch(void* const* d_in, const int* in_sizes, int n_in,
                              void* d_out, int out_size, void* d_ws, size_t ws_size,
                              hipStream_t stream) {
    const float* x   = (const float*)d_in[0];
    const float* Wih = (const float*)d_in[1];
    const float* Whh = (const float*)d_in[2];
    const float* Qir = (const float*)d_in[3];
    const float* Qib = (const float*)d_in[4];
    const float* Kir = (const float*)d_in[5];
    const float* Vir = (const float*)d_in[6];
    const float* Qrr = (const float*)d_in[7];
    const float* Krr = (const float*)d_in[8];
    const float* Vrr = (const float*)d_in[9];
    float* out = (float*)d_out;
    float* ws  = (float*)d_ws;

    // ws layout (floats): total ~34.0M floats = ~136 MB
    float* hs   = ws;                  // 16777216  (S,B,R,H)
    float* h1   = ws + 16777216;       // 16777216  (S,B,R,H)
    float* KirT = ws + 33554432;       // 65536     (S,H)
    float* VirT = ws + 33619968;       // 65536     (S,H)
    float* VrrT = ws + 33685504;       // 16384     (H,H)
    float* kb   = ws + 33701888;       // 81920     (B,I,H)
    float* vb   = ws + 33783808;       // 81920     (B,I,H)
    float* KQ   = ws + 33865728;       // 81920     (B,I,H)
    float* cb   = ws + 33947648;       // 640       (B,I)
    float* Mm   = ws + 33948288;       // 16384     (H,H)
    int*   widx = (int*)(ws + 33964672); // 49152 ints (S,B,3)

    (void)in_sizes; (void)n_in; (void)out_size; (void)ws_size;

    kT  <<<576, 256, 0, stream>>>(Kir, Vir, Vrr, KirT, VirT, VrrT);
    kKV <<<640, 128, 0, stream>>>(x, KirT, VirT, kb, vb);
    kKQ <<<640, 128, 0, stream>>>(kb, Qir, Qib, KQ, cb);
    kM  <<<64, 256, 0, stream>>>(Qrr, Krr, Mm);
    kGRU<<<256, 512, 0, stream>>>(x, Wih, Whh, hs);
    kS1 <<<1024, 256, 0, stream>>>(hs, KQ, cb, vb, h1, widx);
    kS2 <<<1024, 256, 131072, stream>>>(h1, widx, Mm, VrrT, out);
}

// Round 2
// 686.280 us; speedup vs baseline: 1.9511x; 1.9511x over previous
//
#include <hip/hip_runtime.h>
#include <math.h>

// Problem constants: S=512, B=32, R=8, H=128, TOP=3, CHL=19, I=20
//
// Pipeline:
//  kT   : transpose Kir,Vir (H,S)->(S,H) and Vrr (H,H)->(H,H)^T
//  kKV  : k[b,i,o], v[b,i,o]  (i=0 null -> 0)
//  kKQ  : KQ[b,i,h] = sum_o k[b,i,o]*Qir[o,h];  cb[b,i] = k[b,i,:].Qir_b
//  kM   : M = Qrr^T @ Krr   (for qk2 = h1 M h1^T)
//  kGRU : 512-step GRU, one block per (r,b), h -> hs (S,B,R,H)
//  kS1  : stage-1 attention via KQ fold, softmax, top-3 -> h1, widx, zero losers in out
//  kG1  : T1 = gather(h1,widx) @ M          (winners-only SGEMM, 49152x128 @ 128x128)
//  kS2c : per-pair wave: qk2 = T1.h1, softmax, u = s2@h1 -> U (register-only)
//  kG2  : out[winner] = gather(h1) + U @ VrrT (SGEMM + scatter epilogue)

// ---------------- transposes ----------------
__global__ void kT(const float* __restrict__ Kir, const float* __restrict__ Vir,
                   const float* __restrict__ Vrr,
                   float* __restrict__ KirT, float* __restrict__ VirT,
                   float* __restrict__ VrrT) {
    int idx = blockIdx.x * 256 + threadIdx.x;
    if (idx < 65536) {
        int s = idx >> 7, o = idx & 127;
        KirT[idx] = Kir[o * 512 + s];
    } else if (idx < 131072) {
        int j = idx - 65536;
        int s = j >> 7, o = j & 127;
        VirT[j] = Vir[o * 512 + s];
    } else if (idx < 147456) {
        int j = idx - 131072;
        int g = j >> 7, h = j & 127;
        VrrT[j] = Vrr[h * 128 + g];
    }
}

// ---------------- k, v ----------------
__global__ __launch_bounds__(128) void kKV(const float* __restrict__ x,
        const float* __restrict__ KirT, const float* __restrict__ VirT,
        float* __restrict__ kbuf, float* __restrict__ vbuf) {
    const int b = blockIdx.x / 20, i = blockIdx.x % 20;
    const int o = threadIdx.x;
    if (i == 0) {  // null channel: x_bis[b,0,:] == 0
        kbuf[(b * 20) * 128 + o] = 0.0f;
        vbuf[(b * 20) * 128 + o] = 0.0f;
        return;
    }
    __shared__ float xL[512];
    for (int idx = threadIdx.x; idx < 512; idx += 128)
        xL[idx] = x[(b * 19 + (i - 1)) * 512 + idx];
    __syncthreads();
    float ak = 0.0f, av = 0.0f;
#pragma unroll 4
    for (int s = 0; s < 512; ++s) {
        float xv = xL[s];
        ak += xv * KirT[s * 128 + o];
        av += xv * VirT[s * 128 + o];
    }
    kbuf[(b * 20 + i) * 128 + o] = ak;
    vbuf[(b * 20 + i) * 128 + o] = av;
}

// ---------------- KQ fold + cb ----------------
__global__ __launch_bounds__(128) void kKQ(const float* __restrict__ kbuf,
        const float* __restrict__ Qir, const float* __restrict__ Qib,
        float* __restrict__ KQ, float* __restrict__ cb) {
    const int b = blockIdx.x / 20, i = blockIdx.x % 20;
    const int h = threadIdx.x;
    __shared__ float kL[128];
    kL[h] = kbuf[(b * 20 + i) * 128 + h];
    __syncthreads();
    float acc = 0.0f;
#pragma unroll 4
    for (int o = 0; o < 128; ++o) acc += kL[o] * Qir[o * 128 + h];
    KQ[(b * 20 + i) * 128 + h] = acc;
    if (h == 0) {
        float c = 0.0f;
        for (int o = 0; o < 128; ++o) c += kL[o] * Qib[o];
        cb[b * 20 + i] = c;
    }
}

// ---------------- M = Qrr^T @ Krr ----------------
__global__ __launch_bounds__(256) void kM(const float* __restrict__ Qrr,
        const float* __restrict__ Krr, float* __restrict__ M) {
    const int h = blockIdx.x * 2 + (threadIdx.x >> 7);
    const int g = threadIdx.x & 127;
    float acc = 0.0f;
#pragma unroll 4
    for (int o = 0; o < 128; ++o) acc += Qrr[o * 128 + h] * Krr[o * 128 + g];
    M[h * 128 + g] = acc;
}

// ---------------- GRU ----------------
__global__ __launch_bounds__(512) void kGRU(const float* __restrict__ x,
        const float* __restrict__ Wih, const float* __restrict__ Whh,
        float* __restrict__ hs) {
    const int r = blockIdx.x >> 5;
    const int b = blockIdx.x & 31;
    const int t = threadIdx.x;
    const int j = t & 127;
    const int kq = t >> 7;

    __shared__ __align__(16) float xT[512 * 20];  // [s][c] (c=0..18 used)
    __shared__ __align__(16) float hL[128];
    __shared__ float part[4][3][128];             // [kq][gate][j]
    __shared__ float xnL[128];                    // n-gate x-part (kept separate)

    for (int idx = t; idx < 19 * 512; idx += 512) {
        int c = idx >> 9, s = idx & 511;
        xT[s * 20 + c] = x[(b * 19 + c) * 512 + s];
    }
    if (t < 128) hL[t] = 0.0f;

    float w0[32], w1[32], w2[32];
    {
        const float* Wb = Whh + (r * 384) * 128 + kq * 32;
        const float4* s0p = (const float4*)(Wb + (j) * 128);
        const float4* s1p = (const float4*)(Wb + (j + 128) * 128);
        const float4* s2p = (const float4*)(Wb + (j + 256) * 128);
#pragma unroll
        for (int u = 0; u < 8; ++u) {
            float4 a = s0p[u]; w0[4*u] = a.x; w0[4*u+1] = a.y; w0[4*u+2] = a.z; w0[4*u+3] = a.w;
            float4 bb = s1p[u]; w1[4*u] = bb.x; w1[4*u+1] = bb.y; w1[4*u+2] = bb.z; w1[4*u+3] = bb.w;
            float4 cc = s2p[u]; w2[4*u] = cc.x; w2[4*u+1] = cc.y; w2[4*u+2] = cc.z; w2[4*u+3] = cc.w;
        }
    }
    float wi[19];
    if (kq < 3) {
        const float* W = Wih + (r * 384 + (j + 128 * kq)) * 20;
#pragma unroll
        for (int c = 0; c < 19; ++c) wi[c] = W[c + 1];  // col 0 is null channel
    }
    __syncthreads();

    const int outBase = (b * 8 + r) * 128 + j;
    for (int s = 0; s < 512; ++s) {
        float4 hv[8];
        const float4* hp4 = ((const float4*)hL) + kq * 8;
#pragma unroll
        for (int u = 0; u < 8; ++u) hv[u] = hp4[u];
        float p0 = 0.0f, p1 = 0.0f, p2 = 0.0f;
#pragma unroll
        for (int u = 0; u < 8; ++u) {
            float4 h4 = hv[u];
            p0 += w0[4*u+0]*h4.x; p1 += w1[4*u+0]*h4.x; p2 += w2[4*u+0]*h4.x;
            p0 += w0[4*u+1]*h4.y; p1 += w1[4*u+1]*h4.y; p2 += w2[4*u+1]*h4.y;
            p0 += w0[4*u+2]*h4.z; p1 += w1[4*u+2]*h4.z; p2 += w2[4*u+2]*h4.z;
            p0 += w0[4*u+3]*h4.w; p1 += w1[4*u+3]*h4.w; p2 += w2[4*u+3]*h4.w;
        }
        if (kq < 3) {
            const float4* xp4 = (const float4*)(xT + s * 20);
            float4 xa = xp4[0], xb = xp4[1], xc = xp4[2], xd = xp4[3], xe = xp4[4];
            float xp = wi[0]*xa.x + wi[1]*xa.y + wi[2]*xa.z + wi[3]*xa.w
                     + wi[4]*xb.x + wi[5]*xb.y + wi[6]*xb.z + wi[7]*xb.w
                     + wi[8]*xc.x + wi[9]*xc.y + wi[10]*xc.z + wi[11]*xc.w
                     + wi[12]*xd.x + wi[13]*xd.y + wi[14]*xd.z + wi[15]*xd.w
                     + wi[16]*xe.x + wi[17]*xe.y + wi[18]*xe.z;
            if (kq == 0) p0 += xp;
            else if (kq == 1) p1 += xp;
            else xnL[j] = xp;   // n-gate x-part must stay un-merged
        }
        part[kq][0][j] = p0;
        part[kq][1][j] = p1;
        part[kq][2][j] = p2;
        __syncthreads();
        if (t < 128) {
            float ar = part[0][0][t] + part[1][0][t] + part[2][0][t] + part[3][0][t];
            float az = part[0][1][t] + part[1][1][t] + part[2][1][t] + part[3][1][t];
            float hn = part[0][2][t] + part[1][2][t] + part[2][2][t] + part[3][2][t];
            float rg = 1.0f / (1.0f + expf(-ar));
            float zg = 1.0f / (1.0f + expf(-az));
            float ng = tanhf(xnL[t] + rg * hn);
            float hprev = hL[t];
            float hnew = (1.0f - zg) * ng + zg * hprev;
            hL[t] = hnew;
            hs[s * (32 * 8 * 128) + outBase] = hnew;
        }
        __syncthreads();
    }
}

// ---------------- stage 1 ----------------
__global__ __launch_bounds__(256) void kS1(const float* __restrict__ hs,
        const float* __restrict__ KQ, const float* __restrict__ cb,
        const float* __restrict__ vbuf,
        float* __restrict__ h1, int* __restrict__ widx, float* __restrict__ out) {
    const int b = blockIdx.x & 31;
    const int s0 = (blockIdx.x >> 5) * 16;
    const int t = threadIdx.x;
    __shared__ float KQL[20 * 132];
    __shared__ float vL[20 * 128];
    __shared__ float cbL[20];
    __shared__ float hLt[8 * 132];
    __shared__ float qkL[8 * 20];
    __shared__ float sfL[8 * 20];
    __shared__ float s0L[8];
    __shared__ int wselL[3];

    for (int idx = t; idx < 2560; idx += 256) {
        int i = idx >> 7, h = idx & 127;
        KQL[i * 132 + h] = KQ[(b * 20 + i) * 128 + h];
        vL[i * 128 + h] = vbuf[(b * 20 + i) * 128 + h];
    }
    if (t < 20) cbL[t] = cb[b * 20 + t];
    __syncthreads();

    for (int p = 0; p < 16; ++p) {
        const int s = s0 + p;
        for (int idx = t; idx < 1024; idx += 256) {
            int r = idx >> 7, h = idx & 127;
            hLt[r * 132 + h] = hs[((s * 32 + b) * 8 + r) * 128 + h];
        }
        __syncthreads();
        if (t < 152) {  // (r, i) with i=1..19; qk[...,0] is exactly 0
            int r = t / 19, i = t % 19 + 1;
            const float* hr = &hLt[r * 132];
            const float* kg = &KQL[i * 132];
            float a = 0.0f;
#pragma unroll 4
            for (int h = 0; h < 128; ++h) a += hr[h] * kg[h];
            qkL[r * 20 + i] = (a + cbL[i]) * 0.08838834764831845f;  // 1/sqrt(128)
        }
        if (t < 8) qkL[t * 20] = 0.0f;
        __syncthreads();
        if (t < 8) {
            float m = -3.4e38f;
            for (int i = 0; i < 20; ++i) m = fmaxf(m, qkL[t * 20 + i]);
            float sum = 0.0f;
            for (int i = 0; i < 20; ++i) {
                float e = expf(qkL[t * 20 + i] - m);
                sfL[t * 20 + i] = e;
                sum += e;
            }
            float inv = 1.0f / sum;
            for (int i = 0; i < 20; ++i) sfL[t * 20 + i] *= inv;
            s0L[t] = sfL[t * 20];
        }
        __syncthreads();
        if (t == 0) {  // 3 smallest soft0; ties -> lower r (stable, matches lax.top_k)
            unsigned chosen = 0;
            for (int n = 0; n < 3; ++n) {
                float best = 3.4e38f; int bi = 0;
                for (int r2 = 0; r2 < 8; ++r2) {
                    if (chosen & (1u << r2)) continue;
                    float v = s0L[r2];
                    if (v < best) { best = v; bi = r2; }
                }
                chosen |= (1u << bi);
                wselL[n] = bi;
                widx[(s * 32 + b) * 3 + n] = bi;
            }
        }
        __syncthreads();
        {
            const int h = t & 127, rq = t >> 7;
            float a0 = 0, a1 = 0, a2 = 0, a3 = 0;
            for (int i = 1; i < 20; ++i) {  // v[b,0,:]==0, skip
                float vv = vL[i * 128 + h];
                a0 += sfL[(rq * 4 + 0) * 20 + i] * vv;
                a1 += sfL[(rq * 4 + 1) * 20 + i] * vv;
                a2 += sfL[(rq * 4 + 2) * 20 + i] * vv;
                a3 += sfL[(rq * 4 + 3) * 20 + i] * vv;
            }
            const int pairBase = (s * 32 + b) * 8;
            float av[4] = {a0, a1, a2, a3};
#pragma unroll
            for (int jj = 0; jj < 4; ++jj) {
                int rim = rq * 4 + jj;
                h1[(pairBase + rim) * 128 + h] = av[jj];
                bool win = (wselL[0] == rim) || (wselL[1] == rim) || (wselL[2] == rim);
                if (!win) out[(pairBase + rim) * 128 + h] = 0.0f;  // losers are exact zeros
            }
        }
        __syncthreads();
    }
}

// ---------------- stage-2 GEMMs ----------------
// EPI=0: C[n][g] = sum_h h1[pair(n)*8 + widx[n]][h] * Bm[h][g]            (T1)
// EPI=1: out[pair*8+widx[n]][c] = h1[same row][c] + sum_g U[n][g]*Bm[g][c]
template<int EPI>
__global__ __launch_bounds__(256) void kGemm(
        const float* __restrict__ Asrc,   // EPI0: h1 (gathered); EPI1: U (dense)
        const float* __restrict__ Bm,     // M or VrrT (128x128 row-major, k-major)
        const int* __restrict__ widx,
        const float* __restrict__ h1g,    // EPI1: h1 for the residual add
        float* __restrict__ C) {
    __shared__ float ALt[64][132];        // [k][row], transposed A chunk
    __shared__ float BL[64][128];         // [k][swizzled col]
    const int n0 = blockIdx.x * 128;
    const int t = threadIdx.x;
    const int tr = t >> 4, tc = t & 15;   // 8 rows x 8 cols micro-tile
    const int q0 = 2 * tc, q1 = 2 * tc + 1;
    const int bq0 = (q0 ^ (q0 >> 3)) * 4; // swizzled float offsets of this thread's quads
    const int bq1 = (q1 ^ (q1 >> 3)) * 4;
    float acc[8][8];
#pragma unroll
    for (int i = 0; i < 8; ++i)
#pragma unroll
        for (int jj = 0; jj < 8; ++jj) acc[i][jj] = 0.0f;

    for (int kc = 0; kc < 128; kc += 64) {
        __syncthreads();
        // stage A transposed: 128 rows x 64 k
#pragma unroll
        for (int i = 0; i < 8; ++i) {
            int idx = t + i * 256;
            int row = idx >> 4, qk = idx & 15;
            const float* src;
            if (EPI == 0) {
                int n = n0 + row;
                int pair = n / 3;
                int rim = widx[n];
                src = Asrc + ((pair << 3) + rim) * 128 + kc + qk * 4;
            } else {
                src = Asrc + (n0 + row) * 128 + kc + qk * 4;
            }
            float4 a = *(const float4*)src;
            ALt[qk * 4 + 0][row] = a.x;
            ALt[qk * 4 + 1][row] = a.y;
            ALt[qk * 4 + 2][row] = a.z;
            ALt[qk * 4 + 3][row] = a.w;
        }
        // stage B with quad-XOR swizzle (kills 4-way b128 column conflicts)
#pragma unroll
        for (int i = 0; i < 8; ++i) {
            int idx = t + i * 256;
            int kk = idx >> 5, qc = idx & 31;
            float4 bv = *(const float4*)(Bm + (kc + kk) * 128 + qc * 4);
            int pos = (qc ^ (qc >> 3)) * 4;
            *(float4*)&BL[kk][pos] = bv;
        }
        __syncthreads();
#pragma unroll 2
        for (int k = 0; k < 64; ++k) {
            float4 a0 = *(const float4*)&ALt[k][8 * tr];
            float4 a1 = *(const float4*)&ALt[k][8 * tr + 4];
            float4 b0 = *(const float4*)&BL[k][bq0];
            float4 b1 = *(const float4*)&BL[k][bq1];
            float ar[8] = {a0.x, a0.y, a0.z, a0.w, a1.x, a1.y, a1.z, a1.w};
            float bc[8] = {b0.x, b0.y, b0.z, b0.w, b1.x, b1.y, b1.z, b1.w};
#pragma unroll
            for (int i = 0; i < 8; ++i)
#pragma unroll
                for (int jj = 0; jj < 8; ++jj) acc[i][jj] += ar[i] * bc[jj];
        }
    }
    if (EPI == 0) {
#pragma unroll
        for (int i = 0; i < 8; ++i) {
            int row = n0 + 8 * tr + i;
            *(float4*)(C + row * 128 + 8 * tc) =
                make_float4(acc[i][0], acc[i][1], acc[i][2], acc[i][3]);
            *(float4*)(C + row * 128 + 8 * tc + 4) =
                make_float4(acc[i][4], acc[i][5], acc[i][6], acc[i][7]);
        }
    } else {
#pragma unroll
        for (int i = 0; i < 8; ++i) {
            int n = n0 + 8 * tr + i;
            int pair = n / 3;
            int rim = widx[n];
            int base = ((pair << 3) + rim) * 128 + 8 * tc;
            float4 w0 = *(const float4*)(h1g + base);
            float4 w1 = *(const float4*)(h1g + base + 4);
            *(float4*)(C + base) = make_float4(acc[i][0] + w0.x, acc[i][1] + w0.y,
                                               acc[i][2] + w0.z, acc[i][3] + w0.w);
            *(float4*)(C + base + 4) = make_float4(acc[i][4] + w1.x, acc[i][5] + w1.y,
                                                   acc[i][6] + w1.z, acc[i][7] + w1.w);
        }
    }
}

// ---------------- stage-2 core: qk2 + softmax + u (one wave per pair) ----------------
__global__ __launch_bounds__(256) void kS2c(const float* __restrict__ T1,
        const float* __restrict__ h1, float* __restrict__ U) {
    const int w = threadIdx.x >> 6;
    const int lane = threadIdx.x & 63;
    const int p = blockIdx.x * 4 + w;
    const int base8 = p * 8 * 128;
    float hv0[8], hv1[8];
#pragma unroll
    for (int c = 0; c < 8; ++c) {
        hv0[c] = h1[base8 + c * 128 + lane];
        hv1[c] = h1[base8 + c * 128 + 64 + lane];
    }
    float t0[3], t1v[3];
#pragma unroll
    for (int wr = 0; wr < 3; ++wr) {
        t0[wr]  = T1[(p * 3 + wr) * 128 + lane];
        t1v[wr] = T1[(p * 3 + wr) * 128 + 64 + lane];
    }
    float pr[3][8];
#pragma unroll
    for (int wr = 0; wr < 3; ++wr)
#pragma unroll
        for (int c = 0; c < 8; ++c)
            pr[wr][c] = t0[wr] * hv0[c] + t1v[wr] * hv1[c];
#pragma unroll
    for (int off = 32; off > 0; off >>= 1)
#pragma unroll
        for (int wr = 0; wr < 3; ++wr)
#pragma unroll
            for (int c = 0; c < 8; ++c)
                pr[wr][c] += __shfl_xor(pr[wr][c], off, 64);
#pragma unroll
    for (int wr = 0; wr < 3; ++wr) {
        float m = pr[wr][0];
#pragma unroll
        for (int c = 1; c < 8; ++c) m = fmaxf(m, pr[wr][c]);
        float sum = 0.0f;
#pragma unroll
        for (int c = 0; c < 8; ++c) { pr[wr][c] = expf(pr[wr][c] - m); sum += pr[wr][c]; }
        float inv = 1.0f / sum;
        float u0 = 0.0f, u1 = 0.0f;
#pragma unroll
        for (int c = 0; c < 8; ++c) {
            float sv = pr[wr][c] * inv;
            u0 += sv * hv0[c];
            u1 += sv * hv1[c];
        }
        U[(p * 3 + wr) * 128 + lane] = u0;
        U[(p * 3 + wr) * 128 + 64 + lane] = u1;
    }
}

extern "C" void kernel_launch(void* const* d_in, const int* in_sizes, int n_in,
                              void* d_out, int out_size, void* d_ws, size_t ws_size,
                              hipStream_t stream) {
    const float* x   = (const float*)d_in[0];
    const float* Wih = (const float*)d_in[1];
    const float* Whh = (const float*)d_in[2];
    const float* Qir = (const float*)d_in[3];
    const float* Qib = (const float*)d_in[4];
    const float* Kir = (const float*)d_in[5];
    const float* Vir = (const float*)d_in[6];
    const float* Qrr = (const float*)d_in[7];
    const float* Krr = (const float*)d_in[8];
    const float* Vrr = (const float*)d_in[9];
    float* out = (float*)d_out;
    float* ws  = (float*)d_ws;

    // ws layout (floats): total ~34.0M floats = ~136 MB
    float* hs   = ws;                  // 16777216  (S,B,R,H) -- dead after kS1
    float* h1   = ws + 16777216;       // 16777216  (S,B,R,H)
    float* KirT = ws + 33554432;       // 65536
    float* VirT = ws + 33619968;       // 65536
    float* VrrT = ws + 33685504;       // 16384
    float* kb   = ws + 33701888;       // 81920
    float* vb   = ws + 33783808;       // 81920
    float* KQ   = ws + 33865728;       // 81920
    float* cb   = ws + 33947648;       // 640
    float* Mm   = ws + 33948288;       // 16384
    int*   widx = (int*)(ws + 33964672); // 49152 ints (S,B,3)
    // stage-2 temporaries overlap the (dead) hs region:
    float* T1   = ws;                  // 6291456   (49152,128)
    float* U    = ws + 6291456;        // 6291456   (49152,128)

    (void)in_sizes; (void)n_in; (void)out_size; (void)ws_size;

    kT  <<<576, 256, 0, stream>>>(Kir, Vir, Vrr, KirT, VirT, VrrT);
    kKV <<<640, 128, 0, stream>>>(x, KirT, VirT, kb, vb);
    kKQ <<<640, 128, 0, stream>>>(kb, Qir, Qib, KQ, cb);
    kM  <<<64, 256, 0, stream>>>(Qrr, Krr, Mm);
    kGRU<<<256, 512, 0, stream>>>(x, Wih, Whh, hs);
    kS1 <<<1024, 256, 0, stream>>>(hs, KQ, cb, vb, h1, widx, out);
    kGemm<0><<<384, 256, 0, stream>>>(h1, Mm, widx, nullptr, T1);
    kS2c<<<4096, 256, 0, stream>>>(T1, h1, U);
    kGemm<1><<<384, 256, 0, stream>>>(U, VrrT, widx, h1, out);
}

// Round 3
// 608.849 us; speedup vs baseline: 2.1992x; 1.1272x over previous
//
#include <hip/hip_runtime.h>
#include <math.h>

// Problem constants: S=512, B=32, R=8, H=128, TOP=3, CHL=19, I=20
//
// Pipeline:
//  kT   : transpose Kir,Vir (H,S)->(S,H) and Vrr (H,H)->(H,H)^T
//  kKV  : k[b,i,o], v[b,i,o]  (i=0 null -> 0)
//  kKQ  : KQ[b,i,h] = sum_o k[b,i,o]*Qir[o,h];  cb[b,i] = k[b,i,:].Qir_b
//  kM   : M = Qrr^T @ Krr   (for qk2 = h1 M h1^T)
//  kGRU : 512-step GRU, one block per (r,b); DPP quad-reduce, LDS hs buffer
//  kS1  : stage-1 attention via KQ fold, softmax, top-3 -> h1, widx, zero losers in out
//  kG1  : T1 = gather(h1,widx) @ M          (winners-only SGEMM, 49152x128 @ 128x128)
//  kS2c : per-pair wave: qk2 = T1.h1, softmax, u = s2@h1 -> U (register-only)
//  kG2  : out[winner] = gather(h1) + U @ VrrT (SGEMM + scatter epilogue)

// ---------------- transposes ----------------
__global__ void kT(const float* __restrict__ Kir, const float* __restrict__ Vir,
                   const float* __restrict__ Vrr,
                   float* __restrict__ KirT, float* __restrict__ VirT,
                   float* __restrict__ VrrT) {
    int idx = blockIdx.x * 256 + threadIdx.x;
    if (idx < 65536) {
        int s = idx >> 7, o = idx & 127;
        KirT[idx] = Kir[o * 512 + s];
    } else if (idx < 131072) {
        int j = idx - 65536;
        int s = j >> 7, o = j & 127;
        VirT[j] = Vir[o * 512 + s];
    } else if (idx < 147456) {
        int j = idx - 131072;
        int g = j >> 7, h = j & 127;
        VrrT[j] = Vrr[h * 128 + g];
    }
}

// ---------------- k, v ----------------
__global__ __launch_bounds__(128) void kKV(const float* __restrict__ x,
        const float* __restrict__ KirT, const float* __restrict__ VirT,
        float* __restrict__ kbuf, float* __restrict__ vbuf) {
    const int b = blockIdx.x / 20, i = blockIdx.x % 20;
    const int o = threadIdx.x;
    if (i == 0) {  // null channel: x_bis[b,0,:] == 0
        kbuf[(b * 20) * 128 + o] = 0.0f;
        vbuf[(b * 20) * 128 + o] = 0.0f;
        return;
    }
    __shared__ float xL[512];
    for (int idx = threadIdx.x; idx < 512; idx += 128)
        xL[idx] = x[(b * 19 + (i - 1)) * 512 + idx];
    __syncthreads();
    float ak = 0.0f, av = 0.0f;
#pragma unroll 4
    for (int s = 0; s < 512; ++s) {
        float xv = xL[s];
        ak += xv * KirT[s * 128 + o];
        av += xv * VirT[s * 128 + o];
    }
    kbuf[(b * 20 + i) * 128 + o] = ak;
    vbuf[(b * 20 + i) * 128 + o] = av;
}

// ---------------- KQ fold + cb ----------------
__global__ __launch_bounds__(128) void kKQ(const float* __restrict__ kbuf,
        const float* __restrict__ Qir, const float* __restrict__ Qib,
        float* __restrict__ KQ, float* __restrict__ cb) {
    const int b = blockIdx.x / 20, i = blockIdx.x % 20;
    const int h = threadIdx.x;
    __shared__ float kL[128];
    kL[h] = kbuf[(b * 20 + i) * 128 + h];
    __syncthreads();
    float acc = 0.0f;
#pragma unroll 4
    for (int o = 0; o < 128; ++o) acc += kL[o] * Qir[o * 128 + h];
    KQ[(b * 20 + i) * 128 + h] = acc;
    if (h == 0) {
        float c = 0.0f;
        for (int o = 0; o < 128; ++o) c += kL[o] * Qib[o];
        cb[b * 20 + i] = c;
    }
}

// ---------------- M = Qrr^T @ Krr ----------------
__global__ __launch_bounds__(256) void kM(const float* __restrict__ Qrr,
        const float* __restrict__ Krr, float* __restrict__ M) {
    const int h = blockIdx.x * 2 + (threadIdx.x >> 7);
    const int g = threadIdx.x & 127;
    float acc = 0.0f;
#pragma unroll 4
    for (int o = 0; o < 128; ++o) acc += Qrr[o * 128 + h] * Krr[o * 128 + g];
    M[h * 128 + g] = acc;
}

// ---------------- GRU ----------------
// grid 256 = (r,b); 512 threads: t = 4*j + kq. The 4 partials of output j
// live in one DPP quad -> quad_perm reduction (pure VALU). h history kept in
// a rolling 64-row LDS buffer, flushed to global every 64 steps.
template<int CTRL>
__device__ __forceinline__ float dppadd(float v) {
    int r = __builtin_amdgcn_update_dpp(0, __float_as_int(v), CTRL, 0xF, 0xF, true);
    return v + __int_as_float(r);
}

__global__ __launch_bounds__(512) void kGRU(const float* __restrict__ x,
        const float* __restrict__ Wih, const float* __restrict__ Whh,
        float* __restrict__ hs) {
    const int r = blockIdx.x >> 5;
    const int b = blockIdx.x & 31;
    const int t = threadIdx.x;
    const int j = t >> 2;
    const int kq = t & 3;

    __shared__ __align__(16) float xT[512 * 20];   // [s][c], c=0..18 used
    __shared__ __align__(16) float hsBuf[64 * 144]; // 64 rows, swizzled 128+pad

    // stage x transposed (coalesced over s)
    for (int idx = t; idx < 19 * 512; idx += 512) {
        int c = idx >> 9, s = idx & 511;
        xT[s * 20 + c] = x[(b * 19 + c) * 512 + s];
    }
    if (t < 144) hsBuf[63 * 144 + t] = 0.0f;  // h(-1) = 0

    // weights: thread owns Whh rows {j, j+128, j+256}, cols [32kq, 32kq+32)
    float w0[32], w1[32], w2[32];
    {
        const float* Wb = Whh + (r * 384) * 128 + kq * 32;
        const float4* s0p = (const float4*)(Wb + (j) * 128);
        const float4* s1p = (const float4*)(Wb + (j + 128) * 128);
        const float4* s2p = (const float4*)(Wb + (j + 256) * 128);
#pragma unroll
        for (int u = 0; u < 8; ++u) {
            float4 a = s0p[u]; w0[4*u] = a.x; w0[4*u+1] = a.y; w0[4*u+2] = a.z; w0[4*u+3] = a.w;
            float4 bb = s1p[u]; w1[4*u] = bb.x; w1[4*u+1] = bb.y; w1[4*u+2] = bb.z; w1[4*u+3] = bb.w;
            float4 cc = s2p[u]; w2[4*u] = cc.x; w2[4*u+1] = cc.y; w2[4*u+2] = cc.z; w2[4*u+3] = cc.w;
        }
    }
    // x-weights: kq0 -> r-gate row j, kq1 -> z-gate row j+128, kq2 -> n-gate row j+256
    float wi[19];
    if (kq < 3) {
        const float* W = Wih + (r * 384 + (j + 128 * kq)) * 20;
#pragma unroll
        for (int c = 0; c < 19; ++c) wi[c] = W[c + 1];  // col 0 is null channel
    } else {
#pragma unroll
        for (int c = 0; c < 19; ++c) wi[c] = 0.0f;
    }
    __syncthreads();

    const int jmap = j + ((j >> 5) << 2);          // swizzled column
    const int cellBase = (b * 8 + r) * 128;
    const int fcb = (t & 7) * 16;                  // flush col base
    const int fmap = fcb + ((fcb >> 5) << 2);
    const int fq = t >> 3;                         // flush row
    float hprev = 0.0f;

    for (int s = 0; s < 512; ++s) {
        const int rowR = (s + 63) & 63;
        const float4* hp4 = (const float4*)(hsBuf + rowR * 144 + kq * 36);
        float4 hv[8];
#pragma unroll
        for (int u = 0; u < 8; ++u) hv[u] = hp4[u];

        float p0 = 0.0f, p1 = 0.0f, p2 = 0.0f;
#pragma unroll
        for (int u = 0; u < 8; ++u) {
            float4 h4 = hv[u];
            p0 += w0[4*u+0]*h4.x; p1 += w1[4*u+0]*h4.x; p2 += w2[4*u+0]*h4.x;
            p0 += w0[4*u+1]*h4.y; p1 += w1[4*u+1]*h4.y; p2 += w2[4*u+1]*h4.y;
            p0 += w0[4*u+2]*h4.z; p1 += w1[4*u+2]*h4.z; p2 += w2[4*u+2]*h4.z;
            p0 += w0[4*u+3]*h4.w; p1 += w1[4*u+3]*h4.w; p2 += w2[4*u+3]*h4.w;
        }
        // x-projection (broadcast reads; all lanes run the 19 FMAs)
        float xp;
        {
            const float4* xp4 = (const float4*)(xT + s * 20);
            float4 xa = xp4[0], xb = xp4[1], xc = xp4[2], xd = xp4[3], xe = xp4[4];
            xp = wi[0]*xa.x + wi[1]*xa.y + wi[2]*xa.z + wi[3]*xa.w
               + wi[4]*xb.x + wi[5]*xb.y + wi[6]*xb.z + wi[7]*xb.w
               + wi[8]*xc.x + wi[9]*xc.y + wi[10]*xc.z + wi[11]*xc.w
               + wi[12]*xd.x + wi[13]*xd.y + wi[14]*xd.z + wi[15]*xd.w
               + wi[16]*xe.x + wi[17]*xe.y + wi[18]*xe.z;
        }
        p0 += (kq == 0) ? xp : 0.0f;
        p1 += (kq == 1) ? xp : 0.0f;
        float p3 = (kq == 2) ? xp : 0.0f;

        // quad reduction: xor1 (0xB1) + xor2 (0x4E); all 4 lanes get full sums
        p0 = dppadd<0xB1>(p0); p0 = dppadd<0x4E>(p0);
        p1 = dppadd<0xB1>(p1); p1 = dppadd<0x4E>(p1);
        p2 = dppadd<0xB1>(p2); p2 = dppadd<0x4E>(p2);
        p3 = dppadd<0xB1>(p3); p3 = dppadd<0x4E>(p3);

        // gates (overflow-safe fast forms)
        float rg = __builtin_amdgcn_rcpf(1.0f + __expf(-p0));
        float zg = __builtin_amdgcn_rcpf(1.0f + __expf(-p1));
        float a  = p3 + rg * p2;
        float ng = 1.0f - 2.0f * __builtin_amdgcn_rcpf(__expf(2.0f * a) + 1.0f);
        float hnew = ng + zg * (hprev - ng);
        hprev = hnew;
        if (kq == 0) hsBuf[(s & 63) * 144 + jmap] = hnew;
        __syncthreads();

        if ((s & 63) == 63) {  // flush 64 steps of h to global, coalesced
            const int sBase = s - 63;
            const float4* src = (const float4*)(hsBuf + fq * 144 + fmap);
            float4 v0 = src[0], v1 = src[1], v2 = src[2], v3 = src[3];
            float4* dst = (float4*)(hs + (size_t)(sBase + fq) * 32768 + cellBase + fcb);
            dst[0] = v0; dst[1] = v1; dst[2] = v2; dst[3] = v3;
            __syncthreads();
        }
    }
}

// ---------------- stage 1 ----------------
__global__ __launch_bounds__(256) void kS1(const float* __restrict__ hs,
        const float* __restrict__ KQ, const float* __restrict__ cb,
        const float* __restrict__ vbuf,
        float* __restrict__ h1, int* __restrict__ widx, float* __restrict__ out) {
    const int b = blockIdx.x & 31;
    const int s0 = (blockIdx.x >> 5) * 16;
    const int t = threadIdx.x;
    __shared__ float KQL[20 * 132];
    __shared__ float vL[20 * 128];
    __shared__ float cbL[20];
    __shared__ float hLt[8 * 132];
    __shared__ float qkL[8 * 20];
    __shared__ float sfL[8 * 20];
    __shared__ float s0L[8];
    __shared__ int wselL[3];

    for (int idx = t; idx < 2560; idx += 256) {
        int i = idx >> 7, h = idx & 127;
        KQL[i * 132 + h] = KQ[(b * 20 + i) * 128 + h];
        vL[i * 128 + h] = vbuf[(b * 20 + i) * 128 + h];
    }
    if (t < 20) cbL[t] = cb[b * 20 + t];
    __syncthreads();

    for (int p = 0; p < 16; ++p) {
        const int s = s0 + p;
        for (int idx = t; idx < 1024; idx += 256) {
            int r = idx >> 7, h = idx & 127;
            hLt[r * 132 + h] = hs[((s * 32 + b) * 8 + r) * 128 + h];
        }
        __syncthreads();
        if (t < 152) {  // (r, i) with i=1..19; qk[...,0] is exactly 0
            int r = t / 19, i = t % 19 + 1;
            const float* hr = &hLt[r * 132];
            const float* kg = &KQL[i * 132];
            float a = 0.0f;
#pragma unroll 4
            for (int h = 0; h < 128; ++h) a += hr[h] * kg[h];
            qkL[r * 20 + i] = (a + cbL[i]) * 0.08838834764831845f;  // 1/sqrt(128)
        }
        if (t < 8) qkL[t * 20] = 0.0f;
        __syncthreads();
        if (t < 8) {
            float m = -3.4e38f;
            for (int i = 0; i < 20; ++i) m = fmaxf(m, qkL[t * 20 + i]);
            float sum = 0.0f;
            for (int i = 0; i < 20; ++i) {
                float e = expf(qkL[t * 20 + i] - m);
                sfL[t * 20 + i] = e;
                sum += e;
            }
            float inv = 1.0f / sum;
            for (int i = 0; i < 20; ++i) sfL[t * 20 + i] *= inv;
            s0L[t] = sfL[t * 20];
        }
        __syncthreads();
        if (t == 0) {  // 3 smallest soft0; ties -> lower r (stable, matches lax.top_k)
            unsigned chosen = 0;
            for (int n = 0; n < 3; ++n) {
                float best = 3.4e38f; int bi = 0;
                for (int r2 = 0; r2 < 8; ++r2) {
                    if (chosen & (1u << r2)) continue;
                    float v = s0L[r2];
                    if (v < best) { best = v; bi = r2; }
                }
                chosen |= (1u << bi);
                wselL[n] = bi;
                widx[(s * 32 + b) * 3 + n] = bi;
            }
        }
        __syncthreads();
        {
            const int h = t & 127, rq = t >> 7;
            float a0 = 0, a1 = 0, a2 = 0, a3 = 0;
            for (int i = 1; i < 20; ++i) {  // v[b,0,:]==0, skip
                float vv = vL[i * 128 + h];
                a0 += sfL[(rq * 4 + 0) * 20 + i] * vv;
                a1 += sfL[(rq * 4 + 1) * 20 + i] * vv;
                a2 += sfL[(rq * 4 + 2) * 20 + i] * vv;
                a3 += sfL[(rq * 4 + 3) * 20 + i] * vv;
            }
            const int pairBase = (s * 32 + b) * 8;
            float av[4] = {a0, a1, a2, a3};
#pragma unroll
            for (int jj = 0; jj < 4; ++jj) {
                int rim = rq * 4 + jj;
                h1[(pairBase + rim) * 128 + h] = av[jj];
                bool win = (wselL[0] == rim) || (wselL[1] == rim) || (wselL[2] == rim);
                if (!win) out[(pairBase + rim) * 128 + h] = 0.0f;  // losers are exact zeros
            }
        }
        __syncthreads();
    }
}

// ---------------- stage-2 GEMMs ----------------
// EPI=0: C[n][g] = sum_h h1[pair(n)*8 + widx[n]][h] * Bm[h][g]            (T1)
// EPI=1: out[pair*8+widx[n]][c] = h1[same row][c] + sum_g U[n][g]*Bm[g][c]
template<int EPI>
__global__ __launch_bounds__(256) void kGemm(
        const float* __restrict__ Asrc,   // EPI0: h1 (gathered); EPI1: U (dense)
        const float* __restrict__ Bm,     // M or VrrT (128x128 row-major, k-major)
        const int* __restrict__ widx,
        const float* __restrict__ h1g,    // EPI1: h1 for the residual add
        float* __restrict__ C) {
    __shared__ float ALt[64][132];        // [k][row], transposed A chunk
    __shared__ float BL[64][128];         // [k][swizzled col]
    const int n0 = blockIdx.x * 128;
    const int t = threadIdx.x;
    const int tr = t >> 4, tc = t & 15;   // 8 rows x 8 cols micro-tile
    const int q0 = 2 * tc, q1 = 2 * tc + 1;
    const int bq0 = (q0 ^ (q0 >> 3)) * 4; // swizzled float offsets of this thread's quads
    const int bq1 = (q1 ^ (q1 >> 3)) * 4;
    float acc[8][8];
#pragma unroll
    for (int i = 0; i < 8; ++i)
#pragma unroll
        for (int jj = 0; jj < 8; ++jj) acc[i][jj] = 0.0f;

    for (int kc = 0; kc < 128; kc += 64) {
        __syncthreads();
        // stage A transposed: 128 rows x 64 k
#pragma unroll
        for (int i = 0; i < 8; ++i) {
            int idx = t + i * 256;
            int row = idx >> 4, qk = idx & 15;
            const float* src;
            if (EPI == 0) {
                int n = n0 + row;
                int pair = n / 3;
                int rim = widx[n];
                src = Asrc + ((pair << 3) + rim) * 128 + kc + qk * 4;
            } else {
                src = Asrc + (n0 + row) * 128 + kc + qk * 4;
            }
            float4 a = *(const float4*)src;
            ALt[qk * 4 + 0][row] = a.x;
            ALt[qk * 4 + 1][row] = a.y;
            ALt[qk * 4 + 2][row] = a.z;
            ALt[qk * 4 + 3][row] = a.w;
        }
        // stage B with quad-XOR swizzle (kills 4-way b128 column conflicts)
#pragma unroll
        for (int i = 0; i < 8; ++i) {
            int idx = t + i * 256;
            int kk = idx >> 5, qc = idx & 31;
            float4 bv = *(const float4*)(Bm + (kc + kk) * 128 + qc * 4);
            int pos = (qc ^ (qc >> 3)) * 4;
            *(float4*)&BL[kk][pos] = bv;
        }
        __syncthreads();
#pragma unroll 2
        for (int k = 0; k < 64; ++k) {
            float4 a0 = *(const float4*)&ALt[k][8 * tr];
            float4 a1 = *(const float4*)&ALt[k][8 * tr + 4];
            float4 b0 = *(const float4*)&BL[k][bq0];
            float4 b1 = *(const float4*)&BL[k][bq1];
            float ar[8] = {a0.x, a0.y, a0.z, a0.w, a1.x, a1.y, a1.z, a1.w};
            float bc[8] = {b0.x, b0.y, b0.z, b0.w, b1.x, b1.y, b1.z, b1.w};
#pragma unroll
            for (int i = 0; i < 8; ++i)
#pragma unroll
                for (int jj = 0; jj < 8; ++jj) acc[i][jj] += ar[i] * bc[jj];
        }
    }
    if (EPI == 0) {
#pragma unroll
        for (int i = 0; i < 8; ++i) {
            int row = n0 + 8 * tr + i;
            *(float4*)(C + row * 128 + 8 * tc) =
                make_float4(acc[i][0], acc[i][1], acc[i][2], acc[i][3]);
            *(float4*)(C + row * 128 + 8 * tc + 4) =
                make_float4(acc[i][4], acc[i][5], acc[i][6], acc[i][7]);
        }
    } else {
#pragma unroll
        for (int i = 0; i < 8; ++i) {
            int n = n0 + 8 * tr + i;
            int pair = n / 3;
            int rim = widx[n];
            int base = ((pair << 3) + rim) * 128 + 8 * tc;
            float4 w0 = *(const float4*)(h1g + base);
            float4 w1 = *(const float4*)(h1g + base + 4);
            *(float4*)(C + base) = make_float4(acc[i][0] + w0.x, acc[i][1] + w0.y,
                                               acc[i][2] + w0.z, acc[i][3] + w0.w);
            *(float4*)(C + base + 4) = make_float4(acc[i][4] + w1.x, acc[i][5] + w1.y,
                                                   acc[i][6] + w1.z, acc[i][7] + w1.w);
        }
    }
}

// ---------------- stage-2 core: qk2 + softmax + u (one wave per pair) ----------------
__global__ __launch_bounds__(256) void kS2c(const float* __restrict__ T1,
        const float* __restrict__ h1, float* __restrict__ U) {
    const int w = threadIdx.x >> 6;
    const int lane = threadIdx.x & 63;
    const int p = blockIdx.x * 4 + w;
    const int base8 = p * 8 * 128;
    float hv0[8], hv1[8];
#pragma unroll
    for (int c = 0; c < 8; ++c) {
        hv0[c] = h1[base8 + c * 128 + lane];
        hv1[c] = h1[base8 + c * 128 + 64 + lane];
    }
    float t0[3], t1v[3];
#pragma unroll
    for (int wr = 0; wr < 3; ++wr) {
        t0[wr]  = T1[(p * 3 + wr) * 128 + lane];
        t1v[wr] = T1[(p * 3 + wr) * 128 + 64 + lane];
    }
    float pr[3][8];
#pragma unroll
    for (int wr = 0; wr < 3; ++wr)
#pragma unroll
        for (int c = 0; c < 8; ++c)
            pr[wr][c] = t0[wr] * hv0[c] + t1v[wr] * hv1[c];
#pragma unroll
    for (int off = 32; off > 0; off >>= 1)
#pragma unroll
        for (int wr = 0; wr < 3; ++wr)
#pragma unroll
            for (int c = 0; c < 8; ++c)
                pr[wr][c] += __shfl_xor(pr[wr][c], off, 64);
#pragma unroll
    for (int wr = 0; wr < 3; ++wr) {
        float m = pr[wr][0];
#pragma unroll
        for (int c = 1; c < 8; ++c) m = fmaxf(m, pr[wr][c]);
        float sum = 0.0f;
#pragma unroll
        for (int c = 0; c < 8; ++c) { pr[wr][c] = expf(pr[wr][c] - m); sum += pr[wr][c]; }
        float inv = 1.0f / sum;
        float u0 = 0.0f, u1 = 0.0f;
#pragma unroll
        for (int c = 0; c < 8; ++c) {
            float sv = pr[wr][c] * inv;
            u0 += sv * hv0[c];
            u1 += sv * hv1[c];
        }
        U[(p * 3 + wr) * 128 + lane] = u0;
        U[(p * 3 + wr) * 128 + 64 + lane] = u1;
    }
}

extern "C" void kernel_launch(void* const* d_in, const int* in_sizes, int n_in,
                              void* d_out, int out_size, void* d_ws, size_t ws_size,
                              hipStream_t stream) {
    const float* x   = (const float*)d_in[0];
    const float* Wih = (const float*)d_in[1];
    const float* Whh = (const float*)d_in[2];
    const float* Qir = (const float*)d_in[3];
    const float* Qib = (const float*)d_in[4];
    const float* Kir = (const float*)d_in[5];
    const float* Vir = (const float*)d_in[6];
    const float* Qrr = (const float*)d_in[7];
    const float* Krr = (const float*)d_in[8];
    const float* Vrr = (const float*)d_in[9];
    float* out = (float*)d_out;
    float* ws  = (float*)d_ws;

    // ws layout (floats): total ~34.0M floats = ~136 MB
    float* hs   = ws;                  // 16777216  (S,B,R,H) -- dead after kS1
    float* h1   = ws + 16777216;       // 16777216  (S,B,R,H)
    float* KirT = ws + 33554432;       // 65536
    float* VirT = ws + 33619968;       // 65536
    float* VrrT = ws + 33685504;       // 16384
    float* kb   = ws + 33701888;       // 81920
    float* vb   = ws + 33783808;       // 81920
    float* KQ   = ws + 33865728;       // 81920
    float* cb   = ws + 33947648;       // 640
    float* Mm   = ws + 33948288;       // 16384
    int*   widx = (int*)(ws + 33964672); // 49152 ints (S,B,3)
    // stage-2 temporaries overlap the (dead) hs region:
    float* T1   = ws;                  // 6291456   (49152,128)
    float* U    = ws + 6291456;        // 6291456   (49152,128)

    (void)in_sizes; (void)n_in; (void)out_size; (void)ws_size;

    kT  <<<576, 256, 0, stream>>>(Kir, Vir, Vrr, KirT, VirT, VrrT);
    kKV <<<640, 128, 0, stream>>>(x, KirT, VirT, kb, vb);
    kKQ <<<640, 128, 0, stream>>>(kb, Qir, Qib, KQ, cb);
    kM  <<<64, 256, 0, stream>>>(Qrr, Krr, Mm);
    kGRU<<<256, 512, 0, stream>>>(x, Wih, Whh, hs);
    kS1 <<<1024, 256, 0, stream>>>(hs, KQ, cb, vb, h1, widx, out);
    kGemm<0><<<384, 256, 0, stream>>>(h1, Mm, widx, nullptr, T1);
    kS2c<<<4096, 256, 0, stream>>>(T1, h1, U);
    kGemm<1><<<384, 256, 0, stream>>>(U, VrrT, widx, h1, out);
}

// Round 4
// 570.406 us; speedup vs baseline: 2.3474x; 1.0674x over previous
//
#include <hip/hip_runtime.h>
#include <math.h>

// Problem constants: S=512, B=32, R=8, H=128, TOP=3, CHL=19, I=20
//
// Pipeline:
//  kT   : transpose Kir,Vir (H,S)->(S,H) and Vrr (H,H)->(H,H)^T
//  kKV  : k[b,i,o], v[b,i,o]  (i=0 null -> 0)
//  kKQ  : KQ[b,i,h] = sum_o k[b,i,o]*Qir[o,h];  cb[b,i] = k[b,i,:].Qir_b
//  kM   : M = Qrr^T @ Krr   (for qk2 = h1 M h1^T)
//  kGRU : 512-step GRU, one block per (r,b); DPP quad-reduce, LDS hs buffer,
//         __launch_bounds__(512,2) so weights live in VGPRs, v_pk_fma_f32 math
//  kS1  : stage-1 attention via KQ fold, softmax, top-3 -> h1, widx, zero losers in out
//  kG1  : T1 = gather(h1,widx) @ M          (winners-only SGEMM, 49152x128 @ 128x128)
//  kS2c : per-pair wave: qk2 = T1.h1, softmax, u = s2@h1 -> U (register-only)
//  kG2  : out[winner] = gather(h1) + U @ VrrT (SGEMM + scatter epilogue)

typedef float v2f __attribute__((ext_vector_type(2)));
__device__ __forceinline__ v2f pkfma(v2f a, v2f b, v2f c) {
    return __builtin_elementwise_fma(a, b, c);
}

// ---------------- transposes ----------------
__global__ void kT(const float* __restrict__ Kir, const float* __restrict__ Vir,
                   const float* __restrict__ Vrr,
                   float* __restrict__ KirT, float* __restrict__ VirT,
                   float* __restrict__ VrrT) {
    int idx = blockIdx.x * 256 + threadIdx.x;
    if (idx < 65536) {
        int s = idx >> 7, o = idx & 127;
        KirT[idx] = Kir[o * 512 + s];
    } else if (idx < 131072) {
        int j = idx - 65536;
        int s = j >> 7, o = j & 127;
        VirT[j] = Vir[o * 512 + s];
    } else if (idx < 147456) {
        int j = idx - 131072;
        int g = j >> 7, h = j & 127;
        VrrT[j] = Vrr[h * 128 + g];
    }
}

// ---------------- k, v ----------------
__global__ __launch_bounds__(128) void kKV(const float* __restrict__ x,
        const float* __restrict__ KirT, const float* __restrict__ VirT,
        float* __restrict__ kbuf, float* __restrict__ vbuf) {
    const int b = blockIdx.x / 20, i = blockIdx.x % 20;
    const int o = threadIdx.x;
    if (i == 0) {  // null channel: x_bis[b,0,:] == 0
        kbuf[(b * 20) * 128 + o] = 0.0f;
        vbuf[(b * 20) * 128 + o] = 0.0f;
        return;
    }
    __shared__ float xL[512];
    for (int idx = threadIdx.x; idx < 512; idx += 128)
        xL[idx] = x[(b * 19 + (i - 1)) * 512 + idx];
    __syncthreads();
    float ak = 0.0f, av = 0.0f;
#pragma unroll 4
    for (int s = 0; s < 512; ++s) {
        float xv = xL[s];
        ak += xv * KirT[s * 128 + o];
        av += xv * VirT[s * 128 + o];
    }
    kbuf[(b * 20 + i) * 128 + o] = ak;
    vbuf[(b * 20 + i) * 128 + o] = av;
}

// ---------------- KQ fold + cb ----------------
__global__ __launch_bounds__(128) void kKQ(const float* __restrict__ kbuf,
        const float* __restrict__ Qir, const float* __restrict__ Qib,
        float* __restrict__ KQ, float* __restrict__ cb) {
    const int b = blockIdx.x / 20, i = blockIdx.x % 20;
    const int h = threadIdx.x;
    __shared__ float kL[128];
    kL[h] = kbuf[(b * 20 + i) * 128 + h];
    __syncthreads();
    float acc = 0.0f;
#pragma unroll 4
    for (int o = 0; o < 128; ++o) acc += kL[o] * Qir[o * 128 + h];
    KQ[(b * 20 + i) * 128 + h] = acc;
    if (h == 0) {
        float c = 0.0f;
        for (int o = 0; o < 128; ++o) c += kL[o] * Qib[o];
        cb[b * 20 + i] = c;
    }
}

// ---------------- M = Qrr^T @ Krr ----------------
__global__ __launch_bounds__(256) void kM(const float* __restrict__ Qrr,
        const float* __restrict__ Krr, float* __restrict__ M) {
    const int h = blockIdx.x * 2 + (threadIdx.x >> 7);
    const int g = threadIdx.x & 127;
    float acc = 0.0f;
#pragma unroll 4
    for (int o = 0; o < 128; ++o) acc += Qrr[o * 128 + h] * Krr[o * 128 + g];
    M[h * 128 + g] = acc;
}

// ---------------- GRU ----------------
// grid 256 = (r,b); 512 threads: t = 4*j + kq. The 4 partials of output j
// live in one DPP quad -> quad_perm reduction (pure VALU). h history kept in
// a rolling 64-row LDS buffer, flushed to global every 64 steps.
template<int CTRL>
__device__ __forceinline__ float dppadd(float v) {
    int r = __builtin_amdgcn_update_dpp(0, __float_as_int(v), CTRL, 0xF, 0xF, true);
    return v + __int_as_float(r);
}

__global__ __launch_bounds__(512, 2) void kGRU(const float* __restrict__ x,
        const float* __restrict__ Wih, const float* __restrict__ Whh,
        float* __restrict__ hs) {
    const int r = blockIdx.x >> 5;
    const int b = blockIdx.x & 31;
    const int t = threadIdx.x;
    const int j = t >> 2;
    const int kq = t & 3;

    __shared__ __align__(16) float xT[512 * 20];    // [s][c], c=0..18 used
    __shared__ __align__(16) float hsBuf[64 * 144]; // 64 rows, swizzled 128+pad

    // stage x transposed (coalesced over s)
    for (int idx = t; idx < 19 * 512; idx += 512) {
        int c = idx >> 9, s = idx & 511;
        xT[s * 20 + c] = x[(b * 19 + c) * 512 + s];
    }
    if (t < 144) hsBuf[63 * 144 + t] = 0.0f;  // h(-1) = 0

    // weights: thread owns Whh rows {j, j+128, j+256}, cols [32kq, 32kq+32)
    v2f w0[16], w1[16], w2[16];
    {
        const float* Wb = Whh + (r * 384) * 128 + kq * 32;
        const float4* s0p = (const float4*)(Wb + (j) * 128);
        const float4* s1p = (const float4*)(Wb + (j + 128) * 128);
        const float4* s2p = (const float4*)(Wb + (j + 256) * 128);
#pragma unroll
        for (int u = 0; u < 8; ++u) {
            float4 a = s0p[u];
            w0[2*u]   = (v2f){a.x, a.y};
            w0[2*u+1] = (v2f){a.z, a.w};
            float4 bb = s1p[u];
            w1[2*u]   = (v2f){bb.x, bb.y};
            w1[2*u+1] = (v2f){bb.z, bb.w};
            float4 cc = s2p[u];
            w2[2*u]   = (v2f){cc.x, cc.y};
            w2[2*u+1] = (v2f){cc.z, cc.w};
        }
    }
    // x-weights: kq0 -> r-gate row j, kq1 -> z-gate row j+128, kq2 -> n-gate row j+256
    v2f wiv[9];
    float wlast;
    if (kq < 3) {
        const float* W = Wih + (r * 384 + (j + 128 * kq)) * 20;
#pragma unroll
        for (int c = 0; c < 9; ++c) wiv[c] = (v2f){W[2*c + 1], W[2*c + 2]};
        wlast = W[19];
    } else {
#pragma unroll
        for (int c = 0; c < 9; ++c) wiv[c] = (v2f){0.0f, 0.0f};
        wlast = 0.0f;
    }
    __syncthreads();

    const int jmap = j + ((j >> 5) << 2);          // swizzled column
    const int cellBase = (b * 8 + r) * 128;
    float hprev = 0.0f;

    for (int s = 0; s < 512; ++s) {
        const int rowR = (s + 63) & 63;
        const float4* hp4 = (const float4*)(hsBuf + rowR * 144 + kq * 36);
        float4 hv[8];
#pragma unroll
        for (int u = 0; u < 8; ++u) hv[u] = hp4[u];

        v2f a0 = {0.0f, 0.0f}, a1 = {0.0f, 0.0f}, a2 = {0.0f, 0.0f};
#pragma unroll
        for (int u = 0; u < 8; ++u) {
            float4 h4 = hv[u];
            v2f hl = (v2f){h4.x, h4.y};
            v2f hh = (v2f){h4.z, h4.w};
            a0 = pkfma(w0[2*u], hl, a0); a0 = pkfma(w0[2*u+1], hh, a0);
            a1 = pkfma(w1[2*u], hl, a1); a1 = pkfma(w1[2*u+1], hh, a1);
            a2 = pkfma(w2[2*u], hl, a2); a2 = pkfma(w2[2*u+1], hh, a2);
        }
        float p0 = a0.x + a0.y;
        float p1 = a1.x + a1.y;
        float p2 = a2.x + a2.y;

        // x-projection (broadcast reads, packed FMAs)
        float xp;
        {
            const float4* xp4 = (const float4*)(xT + s * 20);
            float4 xa = xp4[0], xb = xp4[1], xc = xp4[2], xd = xp4[3], xe = xp4[4];
            v2f xacc = {0.0f, 0.0f};
            xacc = pkfma(wiv[0], (v2f){xa.x, xa.y}, xacc);
            xacc = pkfma(wiv[1], (v2f){xa.z, xa.w}, xacc);
            xacc = pkfma(wiv[2], (v2f){xb.x, xb.y}, xacc);
            xacc = pkfma(wiv[3], (v2f){xb.z, xb.w}, xacc);
            xacc = pkfma(wiv[4], (v2f){xc.x, xc.y}, xacc);
            xacc = pkfma(wiv[5], (v2f){xc.z, xc.w}, xacc);
            xacc = pkfma(wiv[6], (v2f){xd.x, xd.y}, xacc);
            xacc = pkfma(wiv[7], (v2f){xd.z, xd.w}, xacc);
            xacc = pkfma(wiv[8], (v2f){xe.x, xe.y}, xacc);
            xp = xacc.x + xacc.y + wlast * xe.z;
        }
        p0 += (kq == 0) ? xp : 0.0f;
        p1 += (kq == 1) ? xp : 0.0f;
        float p3 = (kq == 2) ? xp : 0.0f;

        // quad reduction: xor1 (0xB1) + xor2 (0x4E); all 4 lanes get full sums
        p0 = dppadd<0xB1>(p0); p0 = dppadd<0x4E>(p0);
        p1 = dppadd<0xB1>(p1); p1 = dppadd<0x4E>(p1);
        p2 = dppadd<0xB1>(p2); p2 = dppadd<0x4E>(p2);
        p3 = dppadd<0xB1>(p3); p3 = dppadd<0x4E>(p3);

        // gates (overflow-safe fast forms)
        float rg = __builtin_amdgcn_rcpf(1.0f + __expf(-p0));
        float zg = __builtin_amdgcn_rcpf(1.0f + __expf(-p1));
        float a  = p3 + rg * p2;
        float ng = 1.0f - 2.0f * __builtin_amdgcn_rcpf(__expf(2.0f * a) + 1.0f);
        float hnew = ng + zg * (hprev - ng);
        hprev = hnew;
        if (kq == 0) hsBuf[(s & 63) * 144 + jmap] = hnew;
        __syncthreads();

        if ((s & 63) == 63) {  // flush 64 steps of h to global, coalesced rows
            const int sBase = s - 63;
            const int c4 = (t & 31) * 4;
            const int cm = c4 + ((c4 >> 5) << 2);
#pragma unroll
            for (int w = 0; w < 4; ++w) {
                int rr = (t >> 5) + w * 16;
                float4 v = *(const float4*)(hsBuf + rr * 144 + cm);
                *(float4*)(hs + (size_t)(sBase + rr) * 32768 + cellBase + c4) = v;
            }
            __syncthreads();
        }
    }
}

// ---------------- stage 1 ----------------
__global__ __launch_bounds__(256) void kS1(const float* __restrict__ hs,
        const float* __restrict__ KQ, const float* __restrict__ cb,
        const float* __restrict__ vbuf,
        float* __restrict__ h1, int* __restrict__ widx, float* __restrict__ out) {
    const int b = blockIdx.x & 31;
    const int s0 = (blockIdx.x >> 5) * 16;
    const int t = threadIdx.x;
    __shared__ float KQL[20 * 132];
    __shared__ float vL[20 * 128];
    __shared__ float cbL[20];
    __shared__ float hLt[8 * 132];
    __shared__ float qkL[8 * 20];
    __shared__ float sfL[8 * 20];
    __shared__ float s0L[8];
    __shared__ int wselL[3];

    for (int idx = t; idx < 2560; idx += 256) {
        int i = idx >> 7, h = idx & 127;
        KQL[i * 132 + h] = KQ[(b * 20 + i) * 128 + h];
        vL[i * 128 + h] = vbuf[(b * 20 + i) * 128 + h];
    }
    if (t < 20) cbL[t] = cb[b * 20 + t];
    __syncthreads();

    for (int p = 0; p < 16; ++p) {
        const int s = s0 + p;
        for (int idx = t; idx < 1024; idx += 256) {
            int r = idx >> 7, h = idx & 127;
            hLt[r * 132 + h] = hs[((s * 32 + b) * 8 + r) * 128 + h];
        }
        __syncthreads();
        if (t < 152) {  // (r, i) with i=1..19; qk[...,0] is exactly 0
            int r = t / 19, i = t % 19 + 1;
            const float* hr = &hLt[r * 132];
            const float* kg = &KQL[i * 132];
            float a = 0.0f;
#pragma unroll 4
            for (int h = 0; h < 128; ++h) a += hr[h] * kg[h];
            qkL[r * 20 + i] = (a + cbL[i]) * 0.08838834764831845f;  // 1/sqrt(128)
        }
        if (t < 8) qkL[t * 20] = 0.0f;
        __syncthreads();
        if (t < 8) {
            float m = -3.4e38f;
            for (int i = 0; i < 20; ++i) m = fmaxf(m, qkL[t * 20 + i]);
            float sum = 0.0f;
            for (int i = 0; i < 20; ++i) {
                float e = expf(qkL[t * 20 + i] - m);
                sfL[t * 20 + i] = e;
                sum += e;
            }
            float inv = 1.0f / sum;
            for (int i = 0; i < 20; ++i) sfL[t * 20 + i] *= inv;
            s0L[t] = sfL[t * 20];
        }
        __syncthreads();
        if (t == 0) {  // 3 smallest soft0; ties -> lower r (stable, matches lax.top_k)
            unsigned chosen = 0;
            for (int n = 0; n < 3; ++n) {
                float best = 3.4e38f; int bi = 0;
                for (int r2 = 0; r2 < 8; ++r2) {
                    if (chosen & (1u << r2)) continue;
                    float v = s0L[r2];
                    if (v < best) { best = v; bi = r2; }
                }
                chosen |= (1u << bi);
                wselL[n] = bi;
                widx[(s * 32 + b) * 3 + n] = bi;
            }
        }
        __syncthreads();
        {
            const int h = t & 127, rq = t >> 7;
            float a0 = 0, a1 = 0, a2 = 0, a3 = 0;
            for (int i = 1; i < 20; ++i) {  // v[b,0,:]==0, skip
                float vv = vL[i * 128 + h];
                a0 += sfL[(rq * 4 + 0) * 20 + i] * vv;
                a1 += sfL[(rq * 4 + 1) * 20 + i] * vv;
                a2 += sfL[(rq * 4 + 2) * 20 + i] * vv;
                a3 += sfL[(rq * 4 + 3) * 20 + i] * vv;
            }
            const int pairBase = (s * 32 + b) * 8;
            float av[4] = {a0, a1, a2, a3};
#pragma unroll
            for (int jj = 0; jj < 4; ++jj) {
                int rim = rq * 4 + jj;
                h1[(pairBase + rim) * 128 + h] = av[jj];
                bool win = (wselL[0] == rim) || (wselL[1] == rim) || (wselL[2] == rim);
                if (!win) out[(pairBase + rim) * 128 + h] = 0.0f;  // losers are exact zeros
            }
        }
        __syncthreads();
    }
}

// ---------------- stage-2 GEMMs ----------------
// EPI=0: C[n][g] = sum_h h1[pair(n)*8 + widx[n]][h] * Bm[h][g]            (T1)
// EPI=1: out[pair*8+widx[n]][c] = h1[same row][c] + sum_g U[n][g]*Bm[g][c]
template<int EPI>
__global__ __launch_bounds__(256) void kGemm(
        const float* __restrict__ Asrc,   // EPI0: h1 (gathered); EPI1: U (dense)
        const float* __restrict__ Bm,     // M or VrrT (128x128 row-major, k-major)
        const int* __restrict__ widx,
        const float* __restrict__ h1g,    // EPI1: h1 for the residual add
        float* __restrict__ C) {
    __shared__ float ALt[64][132];        // [k][row], transposed A chunk
    __shared__ float BL[64][128];         // [k][swizzled col]
    const int n0 = blockIdx.x * 128;
    const int t = threadIdx.x;
    const int tr = t >> 4, tc = t & 15;   // 8 rows x 8 cols micro-tile
    const int q0 = 2 * tc, q1 = 2 * tc + 1;
    const int bq0 = (q0 ^ (q0 >> 3)) * 4; // swizzled float offsets of this thread's quads
    const int bq1 = (q1 ^ (q1 >> 3)) * 4;
    float acc[8][8];
#pragma unroll
    for (int i = 0; i < 8; ++i)
#pragma unroll
        for (int jj = 0; jj < 8; ++jj) acc[i][jj] = 0.0f;

    for (int kc = 0; kc < 128; kc += 64) {
        __syncthreads();
        // stage A transposed: 128 rows x 64 k
#pragma unroll
        for (int i = 0; i < 8; ++i) {
            int idx = t + i * 256;
            int row = idx >> 4, qk = idx & 15;
            const float* src;
            if (EPI == 0) {
                int n = n0 + row;
                int pair = n / 3;
                int rim = widx[n];
                src = Asrc + ((pair << 3) + rim) * 128 + kc + qk * 4;
            } else {
                src = Asrc + (n0 + row) * 128 + kc + qk * 4;
            }
            float4 a = *(const float4*)src;
            ALt[qk * 4 + 0][row] = a.x;
            ALt[qk * 4 + 1][row] = a.y;
            ALt[qk * 4 + 2][row] = a.z;
            ALt[qk * 4 + 3][row] = a.w;
        }
        // stage B with quad-XOR swizzle (kills 4-way b128 column conflicts)
#pragma unroll
        for (int i = 0; i < 8; ++i) {
            int idx = t + i * 256;
            int kk = idx >> 5, qc = idx & 31;
            float4 bv = *(const float4*)(Bm + (kc + kk) * 128 + qc * 4);
            int pos = (qc ^ (qc >> 3)) * 4;
            *(float4*)&BL[kk][pos] = bv;
        }
        __syncthreads();
#pragma unroll 2
        for (int k = 0; k < 64; ++k) {
            float4 a0 = *(const float4*)&ALt[k][8 * tr];
            float4 a1 = *(const float4*)&ALt[k][8 * tr + 4];
            float4 b0 = *(const float4*)&BL[k][bq0];
            float4 b1 = *(const float4*)&BL[k][bq1];
            float ar[8] = {a0.x, a0.y, a0.z, a0.w, a1.x, a1.y, a1.z, a1.w};
            float bc[8] = {b0.x, b0.y, b0.z, b0.w, b1.x, b1.y, b1.z, b1.w};
#pragma unroll
            for (int i = 0; i < 8; ++i)
#pragma unroll
                for (int jj = 0; jj < 8; ++jj) acc[i][jj] += ar[i] * bc[jj];
        }
    }
    if (EPI == 0) {
#pragma unroll
        for (int i = 0; i < 8; ++i) {
            int row = n0 + 8 * tr + i;
            *(float4*)(C + row * 128 + 8 * tc) =
                make_float4(acc[i][0], acc[i][1], acc[i][2], acc[i][3]);
            *(float4*)(C + row * 128 + 8 * tc + 4) =
                make_float4(acc[i][4], acc[i][5], acc[i][6], acc[i][7]);
        }
    } else {
#pragma unroll
        for (int i = 0; i < 8; ++i) {
            int n = n0 + 8 * tr + i;
            int pair = n / 3;
            int rim = widx[n];
            int base = ((pair << 3) + rim) * 128 + 8 * tc;
            float4 w0 = *(const float4*)(h1g + base);
            float4 w1 = *(const float4*)(h1g + base + 4);
            *(float4*)(C + base) = make_float4(acc[i][0] + w0.x, acc[i][1] + w0.y,
                                               acc[i][2] + w0.z, acc[i][3] + w0.w);
            *(float4*)(C + base + 4) = make_float4(acc[i][4] + w1.x, acc[i][5] + w1.y,
                                                   acc[i][6] + w1.z, acc[i][7] + w1.w);
        }
    }
}

// ---------------- stage-2 core: qk2 + softmax + u (one wave per pair) ----------------
__global__ __launch_bounds__(256) void kS2c(const float* __restrict__ T1,
        const float* __restrict__ h1, float* __restrict__ U) {
    const int w = threadIdx.x >> 6;
    const int lane = threadIdx.x & 63;
    const int p = blockIdx.x * 4 + w;
    const int base8 = p * 8 * 128;
    float hv0[8], hv1[8];
#pragma unroll
    for (int c = 0; c < 8; ++c) {
        hv0[c] = h1[base8 + c * 128 + lane];
        hv1[c] = h1[base8 + c * 128 + 64 + lane];
    }
    float t0[3], t1v[3];
#pragma unroll
    for (int wr = 0; wr < 3; ++wr) {
        t0[wr]  = T1[(p * 3 + wr) * 128 + lane];
        t1v[wr] = T1[(p * 3 + wr) * 128 + 64 + lane];
    }
    float pr[3][8];
#pragma unroll
    for (int wr = 0; wr < 3; ++wr)
#pragma unroll
        for (int c = 0; c < 8; ++c)
            pr[wr][c] = t0[wr] * hv0[c] + t1v[wr] * hv1[c];
#pragma unroll
    for (int off = 32; off > 0; off >>= 1)
#pragma unroll
        for (int wr = 0; wr < 3; ++wr)
#pragma unroll
            for (int c = 0; c < 8; ++c)
                pr[wr][c] += __shfl_xor(pr[wr][c], off, 64);
#pragma unroll
    for (int wr = 0; wr < 3; ++wr) {
        float m = pr[wr][0];
#pragma unroll
        for (int c = 1; c < 8; ++c) m = fmaxf(m, pr[wr][c]);
        float sum = 0.0f;
#pragma unroll
        for (int c = 0; c < 8; ++c) { pr[wr][c] = expf(pr[wr][c] - m); sum += pr[wr][c]; }
        float inv = 1.0f / sum;
        float u0 = 0.0f, u1 = 0.0f;
#pragma unroll
        for (int c = 0; c < 8; ++c) {
            float sv = pr[wr][c] * inv;
            u0 += sv * hv0[c];
            u1 += sv * hv1[c];
        }
        U[(p * 3 + wr) * 128 + lane] = u0;
        U[(p * 3 + wr) * 128 + 64 + lane] = u1;
    }
}

extern "C" void kernel_launch(void* const* d_in, const int* in_sizes, int n_in,
                              void* d_out, int out_size, void* d_ws, size_t ws_size,
                              hipStream_t stream) {
    const float* x   = (const float*)d_in[0];
    const float* Wih = (const float*)d_in[1];
    const float* Whh = (const float*)d_in[2];
    const float* Qir = (const float*)d_in[3];
    const float* Qib = (const float*)d_in[4];
    const float* Kir = (const float*)d_in[5];
    const float* Vir = (const float*)d_in[6];
    const float* Qrr = (const float*)d_in[7];
    const float* Krr = (const float*)d_in[8];
    const float* Vrr = (const float*)d_in[9];
    float* out = (float*)d_out;
    float* ws  = (float*)d_ws;

    // ws layout (floats): total ~34.0M floats = ~136 MB
    float* hs   = ws;                  // 16777216  (S,B,R,H) -- dead after kS1
    float* h1   = ws + 16777216;       // 16777216  (S,B,R,H)
    float* KirT = ws + 33554432;       // 65536
    float* VirT = ws + 33619968;       // 65536
    float* VrrT = ws + 33685504;       // 16384
    float* kb   = ws + 33701888;       // 81920
    float* vb   = ws + 33783808;       // 81920
    float* KQ   = ws + 33865728;       // 81920
    float* cb   = ws + 33947648;       // 640
    float* Mm   = ws + 33948288;       // 16384
    int*   widx = (int*)(ws + 33964672); // 49152 ints (S,B,3)
    // stage-2 temporaries overlap the (dead) hs region:
    float* T1   = ws;                  // 6291456   (49152,128)
    float* U    = ws + 6291456;        // 6291456   (49152,128)

    (void)in_sizes; (void)n_in; (void)out_size; (void)ws_size;

    kT  <<<576, 256, 0, stream>>>(Kir, Vir, Vrr, KirT, VirT, VrrT);
    kKV <<<640, 128, 0, stream>>>(x, KirT, VirT, kb, vb);
    kKQ <<<640, 128, 0, stream>>>(kb, Qir, Qib, KQ, cb);
    kM  <<<64, 256, 0, stream>>>(Qrr, Krr, Mm);
    kGRU<<<256, 512, 0, stream>>>(x, Wih, Whh, hs);
    kS1 <<<1024, 256, 0, stream>>>(hs, KQ, cb, vb, h1, widx, out);
    kGemm<0><<<384, 256, 0, stream>>>(h1, Mm, widx, nullptr, T1);
    kS2c<<<4096, 256, 0, stream>>>(T1, h1, U);
    kGemm<1><<<384, 256, 0, stream>>>(U, VrrT, widx, h1, out);
}